// Round 1
// baseline (3407.646 us; speedup 1.0000x reference)
//
#include <hip/hip_runtime.h>

#define B_ 32
#define S_ 64
#define T_ 64
#define H_ 1024
#define V_ 32000

typedef unsigned short u16;
typedef short short8 __attribute__((ext_vector_type(8)));
typedef float f32x4 __attribute__((ext_vector_type(4)));

__device__ inline float bf2f(u16 u) {
    union { unsigned int ui; float f; } c; c.ui = ((unsigned int)u) << 16; return c.f;
}
__device__ inline u16 f2bf(float f) {
    union { float f; unsigned int u; } c; c.f = f;
    unsigned int u = c.u;
    u += 0x7FFFu + ((u >> 16) & 1u);
    return (u16)(u >> 16);
}
__device__ inline float ftanh(float x) {
    float ax = fabsf(x);
    float e = __expf(-2.f * ax);
    float r = (1.f - e) / (1.f + e);
    return copysignf(r, x);
}
__device__ inline float fsigm(float x) { return 1.f / (1.f + __expf(-x)); }

// ---------------------------------------------------------------------------
// Generic 128x128 bf16 MFMA GEMM: C[M=2048,N] = A[2048,K] @ B[N,K]^T + bias
// cmode: 0 = f32 row-major, 1 = logits scatter (m -> t*32+b, write [b,t,v]),
//        2 = bf16 row-major
// ---------------------------------------------------------------------------
__global__ __launch_bounds__(256) void gemm128(
    const u16* __restrict__ A, const u16* __restrict__ Bw,
    const float* __restrict__ bias, void* __restrict__ Cv,
    int N, int K, int cmode)
{
    __shared__ u16 As[128 * 40];
    __shared__ u16 Bs[128 * 40];
    const int tid = threadIdx.x;
    const int n0 = blockIdx.x * 128, m0 = blockIdx.y * 128;
    const int wave = tid >> 6, lane = tid & 63;
    const int wm = wave & 1, wn = wave >> 1;
    const int l16 = lane & 15, qd = lane >> 4;
    f32x4 acc[4][4] = {};

    const int arow = tid >> 1;            // 0..127
    const int akc = (tid & 1) * 16;       // elem offset 0 or 16 within 32-elem row
    const u16* gA = A + (size_t)(m0 + arow) * K + akc;
    const u16* gB = Bw + (size_t)(n0 + arow) * K + akc;

    for (int k0 = 0; k0 < K; k0 += 32) {
        uint4 av0 = *(const uint4*)(gA + k0);
        uint4 av1 = *(const uint4*)(gA + k0 + 8);
        uint4 bv0 = *(const uint4*)(gB + k0);
        uint4 bv1 = *(const uint4*)(gB + k0 + 8);
        __syncthreads();
        *(uint4*)&As[arow * 40 + akc]     = av0;
        *(uint4*)&As[arow * 40 + akc + 8] = av1;
        *(uint4*)&Bs[arow * 40 + akc]     = bv0;
        *(uint4*)&Bs[arow * 40 + akc + 8] = bv1;
        __syncthreads();
        short8 af[4], bfr[4];
#pragma unroll
        for (int i = 0; i < 4; i++)
            af[i] = *(const short8*)&As[(wm * 64 + i * 16 + l16) * 40 + qd * 8];
#pragma unroll
        for (int i = 0; i < 4; i++)
            bfr[i] = *(const short8*)&Bs[(wn * 64 + i * 16 + l16) * 40 + qd * 8];
#pragma unroll
        for (int mi = 0; mi < 4; mi++)
#pragma unroll
            for (int ni = 0; ni < 4; ni++)
                acc[mi][ni] = __builtin_amdgcn_mfma_f32_16x16x32_bf16(
                    af[mi], bfr[ni], acc[mi][ni], 0, 0, 0);
    }

#pragma unroll
    for (int mi = 0; mi < 4; mi++) {
#pragma unroll
        for (int ni = 0; ni < 4; ni++) {
            int ncol = n0 + wn * 64 + ni * 16 + l16;
            float bv = bias ? bias[ncol] : 0.f;
#pragma unroll
            for (int r = 0; r < 4; r++) {
                int mrow = m0 + wm * 64 + mi * 16 + qd * 4 + r;
                float v = acc[mi][ni][r] + bv;
                if (cmode == 0) {
                    ((float*)Cv)[(size_t)mrow * N + ncol] = v;
                } else if (cmode == 1) {
                    int tt = mrow >> 5, bb = mrow & 31;
                    ((float*)Cv)[((size_t)bb * T_ + tt) * V_ + ncol] = v;
                } else {
                    ((u16*)Cv)[(size_t)mrow * N + ncol] = f2bf(v);
                }
            }
        }
    }
}

// ---------------------------------------------------------------------------
// grid barrier: per-block flag cachelines + block-0 aggregation + release flag
// flags at bar[blk*32] (blk 1..255), release at bar[256*32]; sense monotone.
// ---------------------------------------------------------------------------
__device__ inline void gbar(int* bar, int sense)
{
    __syncthreads();   // drains all waves' vmem (compiler emits vmcnt(0) drain)
    if (blockIdx.x == 0) {
        const int tid = threadIdx.x;
        if (tid > 0) {
            while (__hip_atomic_load(&bar[tid * 32], __ATOMIC_RELAXED,
                                     __HIP_MEMORY_SCOPE_AGENT) < sense)
                __builtin_amdgcn_s_sleep(1);
        }
        __syncthreads();
        if (tid == 0) {
            __threadfence();   // wb own L2 + inv for our subsequent reads
            __hip_atomic_store(&bar[256 * 32], sense, __ATOMIC_RELAXED,
                               __HIP_MEMORY_SCOPE_AGENT);
        }
        __syncthreads();       // fence complete before any wave reads
    } else {
        if (threadIdx.x == 0) {
            __threadfence();   // flush this block's writes past L2
            __hip_atomic_store(&bar[blockIdx.x * 32], sense, __ATOMIC_RELAXED,
                               __HIP_MEMORY_SCOPE_AGENT);
            while (__hip_atomic_load(&bar[256 * 32], __ATOMIC_RELAXED,
                                     __HIP_MEMORY_SCOPE_AGENT) < sense)
                __builtin_amdgcn_s_sleep(1);
            __threadfence();   // invalidate L1/L2 before block reads fresh data
        }
        __syncthreads();
    }
}

// ---------------------------------------------------------------------------
// Persistent decode loop: 256 blocks x 256 threads, all 64 steps.
// Block blk: phase A owns qg cols [blk*16, blk*16+16) (Wcat slice in VGPRs).
//            phases B/C: b = blk>>3, g = blk&7 (s-slice / j-slice per g).
// E2 slice [b, all s, 3 seg, j in g*128..+128) staged once in LDS (48KB).
// ---------------------------------------------------------------------------
__global__ __launch_bounds__(256) void k_loop(
    const u16* __restrict__ Wcat, const float* __restrict__ bcat,
    const float* __restrict__ Uk, const float* __restrict__ Va_w,
    const float* __restrict__ Va_b, const u16* __restrict__ E2,
    const float* __restrict__ gix, float* __restrict__ qg,
    float* __restrict__ sc, float* __restrict__ hstate,
    u16* __restrict__ hB, u16* __restrict__ Hall,
    float* __restrict__ out_attn, float* __restrict__ out_hT,
    int* __restrict__ bar)
{
    __shared__ u16 e2s[64 * 384];       // 48KB: [s][seg][jj]
    __shared__ float red[4][32][16];    // 8KB phase-A cross-wave partials
    __shared__ float wl[64];
    __shared__ float pu[3][128];

    const int tid = threadIdx.x;
    const int blk = blockIdx.x;
    const int wave = tid >> 6, lane = tid & 63;
    const int l16 = lane & 15, qd = lane >> 4;
    const int b = blk >> 3, g = blk & 7;

    // --- startup: Wcat B-fragments in registers (reused all 64 steps) ---
    short8 breg[8];
    {
        const u16* wc = Wcat + (size_t)(blk * 16 + l16) * H_ + wave * 256 + qd * 8;
#pragma unroll
        for (int ks = 0; ks < 8; ks++) breg[ks] = *(const short8*)(wc + ks * 32);
    }
    float va[16];
#pragma unroll
    for (int i = 0; i < 16; i++) va[i] = Va_w[i * 64 + lane];
    const float vab = Va_b[0];
    const float bc0 = bcat[blk * 16 + (tid & 15)];   // n = tid&15 for both outputs

    // --- stage E2 slice (once) ---
    {
        const u16* e2g = E2 + (size_t)b * S_ * 3072 + g * 128;
#pragma unroll
        for (int c = 0; c < 12; c++) {
            int o = (c * 256 + tid) * 8;          // u16 offset within slice
            int s = o / 384, rem = o - s * 384;   // 384 u16 per s (3 x 128)
            *(uint4*)&e2s[o] =
                *(const uint4*)(e2g + (size_t)s * 3072 + (rem >> 7) * 1024 + (rem & 127));
        }
    }

    int sense = 0;
    for (int t = 0; t < T_; t++) {
        // ---- phase A: qg[32, blk*16..+16] = hB @ Wcat_slice^T + bcat ----
        f32x4 acc0 = {}, acc1 = {};
        {
            const u16* ha = hB + (size_t)l16 * H_ + wave * 256 + qd * 8;
#pragma unroll
            for (int ks = 0; ks < 8; ks++) {
                short8 a0 = *(const short8*)(ha + ks * 32);
                short8 a1 = *(const short8*)(ha + 16 * H_ + ks * 32);
                acc0 = __builtin_amdgcn_mfma_f32_16x16x32_bf16(a0, breg[ks], acc0, 0, 0, 0);
                acc1 = __builtin_amdgcn_mfma_f32_16x16x32_bf16(a1, breg[ks], acc1, 0, 0, 0);
            }
        }
#pragma unroll
        for (int r = 0; r < 4; r++) {
            red[wave][qd * 4 + r][l16] = acc0[r];
            red[wave][16 + qd * 4 + r][l16] = acc1[r];
        }
        __syncthreads();
        {
            int m = tid >> 4, n = tid & 15;
            float v0 = red[0][m][n] + red[1][m][n] + red[2][m][n] + red[3][m][n] + bc0;
            float v1 = red[0][m + 16][n] + red[1][m + 16][n] +
                       red[2][m + 16][n] + red[3][m + 16][n] + bc0;
            qg[(size_t)m * 4096 + blk * 16 + n] = v0;
            qg[(size_t)(m + 16) * 4096 + blk * 16 + n] = v1;
        }
        gbar(bar, ++sense);

        // ---- phase B: scores for (b, s in [g*8, g*8+8)) ----
        {
            float qreg[16];
            const float* qb = qg + (size_t)b * 4096;
#pragma unroll
            for (int i = 0; i < 16; i++) qreg[i] = qb[i * 64 + lane];
#pragma unroll
            for (int j2 = 0; j2 < 2; j2++) {
                int s = g * 8 + wave * 2 + j2;
                const float* uk = Uk + ((size_t)b * S_ + s) * H_;
                float p = 0.f;
#pragma unroll 4
                for (int i = 0; i < 16; i++)
                    p += va[i] * ftanh(qreg[i] + uk[i * 64 + lane]);
#pragma unroll
                for (int m = 1; m < 64; m <<= 1) p += __shfl_xor(p, m);
                if (lane == 0) sc[b * S_ + s] = p + vab;
            }
        }
        gbar(bar, ++sense);

        // ---- phase C: softmax + ctx@W_ih (via E2) + GRU gates + h update ----
        if (tid < 64) {
            float x = sc[b * S_ + tid];
            float mx = x;
#pragma unroll
            for (int m = 1; m < 64; m <<= 1) mx = fmaxf(mx, __shfl_xor(mx, m));
            float e = __expf(x - mx);
            float ssum = e;
#pragma unroll
            for (int m = 1; m < 64; m <<= 1) ssum += __shfl_xor(ssum, m);
            float w = e / ssum;
            wl[tid] = w;
            if (g == 0) out_attn[(size_t)b * T_ * S_ + (size_t)t * S_ + tid] = w;
        }
        __syncthreads();
        {
            int jj = tid & 127, sh = tid >> 7;
            float p0 = 0.f, p1 = 0.f, p2 = 0.f;
            const u16* e0 = &e2s[sh * 32 * 384 + jj];
#pragma unroll 8
            for (int s = 0; s < 32; s++) {
                float w = wl[sh * 32 + s];
                p0 += w * bf2f(e0[s * 384]);
                p1 += w * bf2f(e0[s * 384 + 128]);
                p2 += w * bf2f(e0[s * 384 + 256]);
            }
            if (sh) { pu[0][jj] = p0; pu[1][jj] = p1; pu[2][jj] = p2; }
            __syncthreads();
            if (!sh) {
                int j = g * 128 + jj;
                const float* gi = gix + ((size_t)t * B_ + b) * 3072;
                const float* gh = qg + (size_t)b * 4096 + 1024;
                float r = fsigm(p0 + pu[0][jj] + gi[j] + gh[j]);
                float z = fsigm(p1 + pu[1][jj] + gi[1024 + j] + gh[1024 + j]);
                float n = ftanh(p2 + pu[2][jj] + gi[2048 + j] + r * gh[2048 + j]);
                float hp = hstate[b * H_ + j];
                float hn = (1.f - z) * n + z * hp;
                hstate[b * H_ + j] = hn;
                hB[b * H_ + j] = f2bf(hn);
                Hall[((size_t)t * B_ + b) * H_ + j] = f2bf(hn);
                if (t == T_ - 1) out_hT[b * H_ + j] = hn;
            }
        }
        gbar(bar, ++sense);
    }
}

// ---------------------------------------------------------------------------
// prologue helpers
// ---------------------------------------------------------------------------
__global__ __launch_bounds__(256) void k_gather(
    const float* __restrict__ emb, const int* __restrict__ target,
    u16* __restrict__ XB)
{
    int m = blockIdx.x;           // 0..2047, m = t*32+b
    int t = m >> 5, b = m & 31;
    int tok = (t == 0) ? 1 : target[b * T_ + (t - 1)];
    float4 v = ((const float4*)(emb + (size_t)tok * H_))[threadIdx.x];
    ushort4 o = { f2bf(v.x), f2bf(v.y), f2bf(v.z), f2bf(v.w) };
    *(ushort4*)&XB[(size_t)m * H_ + threadIdx.x * 4] = o;
}

__global__ __launch_bounds__(256) void k_f2b(
    const float* __restrict__ src, u16* __restrict__ dst, int n4)
{
    int i = blockIdx.x * 256 + threadIdx.x;
    int stride = gridDim.x * 256;
    for (; i < n4; i += stride) {
        float4 v = ((const float4*)src)[i];
        ushort4 o = { f2bf(v.x), f2bf(v.y), f2bf(v.z), f2bf(v.w) };
        ((ushort4*)dst)[i] = o;
    }
}

__global__ __launch_bounds__(256) void k_split(
    const float* __restrict__ W, u16* __restrict__ Wx, u16* __restrict__ Wc)
{
    const int n4 = 3072 * 512;    // W_ih is [3072, 2048] -> 512 float4 per row
    int i = blockIdx.x * 256 + threadIdx.x;
    int stride = gridDim.x * 256;
    for (; i < n4; i += stride) {
        int row = i >> 9;
        int c4 = i & 511;
        float4 v = ((const float4*)W)[i];
        ushort4 o = { f2bf(v.x), f2bf(v.y), f2bf(v.z), f2bf(v.w) };
        if (c4 < 256) *(ushort4*)&Wx[(size_t)row * H_ + c4 * 4] = o;
        else          *(ushort4*)&Wc[(size_t)row * H_ + (c4 - 256) * 4] = o;
    }
}

__global__ __launch_bounds__(256) void k_misc(
    const float* __restrict__ Wa_b, const float* __restrict__ b_hh,
    const float* __restrict__ ehid, float* __restrict__ bcat,
    float* __restrict__ hstate, u16* __restrict__ hB, int* __restrict__ bar)
{
    int i = blockIdx.x * 256 + threadIdx.x;   // grid 128 -> 32768 threads
    if (i < 4096) bcat[i] = (i < 1024) ? Wa_b[i] : b_hh[i - 1024];
    if (i < 8224) bar[i] = 0;                 // zero barrier flags each launch
    if (i < 32768) {
        float v = ehid[i];
        hstate[i] = v;
        hB[i] = f2bf(v);
    }
}

// ---------------------------------------------------------------------------
extern "C" void kernel_launch(void* const* d_in, const int* in_sizes, int n_in,
                              void* d_out, int out_size, void* d_ws, size_t ws_size,
                              hipStream_t stream)
{
    const float* enc   = (const float*)d_in[0];
    const float* ehid  = (const float*)d_in[1];
    const int*   tgt   = (const int*)d_in[2];
    const float* emb   = (const float*)d_in[3];
    const float* Wa_w  = (const float*)d_in[4];
    const float* Wa_b  = (const float*)d_in[5];
    const float* Ua_w  = (const float*)d_in[6];
    const float* Ua_b  = (const float*)d_in[7];
    const float* Va_w  = (const float*)d_in[8];
    const float* Va_b  = (const float*)d_in[9];
    const float* W_ih  = (const float*)d_in[10];
    const float* W_hh  = (const float*)d_in[11];
    const float* b_ih  = (const float*)d_in[12];
    const float* b_hh  = (const float*)d_in[13];
    const float* out_w = (const float*)d_in[14];
    const float* out_b = (const float*)d_in[15];

    char* ws = (char*)d_ws;
    size_t off = 0;
    auto alloc = [&](size_t bytes) {
        void* p = ws + off;
        off += (bytes + 255) & ~(size_t)255;
        return p;
    };
    u16* outB  = (u16*)alloc((size_t)V_ * H_ * 2);
    u16* encB  = (u16*)alloc((size_t)B_ * S_ * H_ * 2);
    u16* UaB   = (u16*)alloc((size_t)H_ * H_ * 2);
    u16* WxB   = (u16*)alloc((size_t)3 * H_ * H_ * 2);
    u16* WcB   = (u16*)alloc((size_t)3 * H_ * H_ * 2);
    u16* WcatB = (u16*)alloc((size_t)4 * H_ * H_ * 2);
    u16* XB    = (u16*)alloc((size_t)T_ * B_ * H_ * 2);
    u16* Hall  = (u16*)alloc((size_t)T_ * B_ * H_ * 2);
    u16* hB    = (u16*)alloc((size_t)B_ * H_ * 2);
    u16* E2    = (u16*)alloc((size_t)B_ * S_ * 3 * H_ * 2);
    float* Uk     = (float*)alloc((size_t)B_ * S_ * H_ * 4);
    float* gix    = (float*)alloc((size_t)T_ * B_ * 3 * H_ * 4);
    float* qg     = (float*)alloc((size_t)B_ * 4 * H_ * 4);
    float* hstate = (float*)alloc((size_t)B_ * H_ * 4);
    float* bcat   = (float*)alloc((size_t)4 * H_ * 4);
    float* sc     = (float*)alloc((size_t)B_ * S_ * 4);
    int*   bar    = (int*)alloc((size_t)(256 * 32 + 32) * 4);

    float* out_logits = (float*)d_out;
    float* out_hT     = out_logits + (size_t)B_ * T_ * V_;
    float* out_attn   = out_hT + (size_t)B_ * H_;

    // --- prologue: conversions / gathers ---
    k_f2b<<<512, 256, 0, stream>>>(out_w, outB, V_ * H_ / 4);
    k_f2b<<<256, 256, 0, stream>>>(enc, encB, B_ * S_ * H_ / 4);
    k_f2b<<<128, 256, 0, stream>>>(Ua_w, UaB, H_ * H_ / 4);
    k_split<<<512, 256, 0, stream>>>(W_ih, WxB, WcB);
    k_f2b<<<128, 256, 0, stream>>>(Wa_w, WcatB, H_ * H_ / 4);
    k_f2b<<<256, 256, 0, stream>>>(W_hh, WcatB + (size_t)H_ * H_, 3 * H_ * H_ / 4);
    k_gather<<<2048, 256, 0, stream>>>(emb, tgt, XB);
    k_misc<<<128, 256, 0, stream>>>(Wa_b, b_hh, ehid, bcat, hstate, hB, bar);

    // --- prologue GEMMs (M = 2048 in all cases) ---
    gemm128<<<dim3(H_ / 128, 16), 256, 0, stream>>>(encB, UaB, Ua_b, (void*)Uk, H_, H_, 0);
    gemm128<<<dim3(3 * H_ / 128, 16), 256, 0, stream>>>(encB, WcB, (const float*)nullptr, (void*)E2, 3 * H_, H_, 2);
    gemm128<<<dim3(3 * H_ / 128, 16), 256, 0, stream>>>(XB, WxB, b_ih, (void*)gix, 3 * H_, H_, 0);

    // --- persistent decode loop: one cooperative kernel for all 64 steps ---
    {
        void* args[] = {
            (void*)&WcatB, (void*)&bcat, (void*)&Uk, (void*)&Va_w, (void*)&Va_b,
            (void*)&E2, (void*)&gix, (void*)&qg, (void*)&sc, (void*)&hstate,
            (void*)&hB, (void*)&Hall, (void*)&out_attn, (void*)&out_hT, (void*)&bar
        };
        hipLaunchCooperativeKernel((const void*)k_loop, dim3(256), dim3(256),
                                   args, 0, stream);
    }

    // --- batched logits GEMM: [2048,1024] @ [32000,1024]^T -> scatter [B,T,V] ---
    gemm128<<<dim3(V_ / 128, 16), 256, 0, stream>>>(Hall, outB, out_b, (void*)out_logits, V_, H_, 1);
}

// Round 2
// 2585.671 us; speedup vs baseline: 1.3179x; 1.3179x over previous
//
#include <hip/hip_runtime.h>

#define B_ 32
#define S_ 64
#define T_ 64
#define H_ 1024
#define V_ 32000

typedef unsigned short u16;
typedef short short8 __attribute__((ext_vector_type(8)));
typedef float f32x4 __attribute__((ext_vector_type(4)));

__device__ inline float bf2f(u16 u) {
    union { unsigned int ui; float f; } c; c.ui = ((unsigned int)u) << 16; return c.f;
}
__device__ inline u16 f2bf(float f) {
    union { float f; unsigned int u; } c; c.f = f;
    unsigned int u = c.u;
    u += 0x7FFFu + ((u >> 16) & 1u);
    return (u16)(u >> 16);
}
__device__ inline float ftanh(float x) {
    float ax = fabsf(x);
    float e = __expf(-2.f * ax);
    float r = (1.f - e) / (1.f + e);
    return copysignf(r, x);
}
__device__ inline float fsigm(float x) { return 1.f / (1.f + __expf(-x)); }

// ---------------------------------------------------------------------------
// Generic 128x128 bf16 MFMA GEMM: C[M=2048,N] = A[2048,K] @ B[N,K]^T + bias
// cmode: 0 = f32 row-major, 1 = logits scatter (m -> t*32+b, write [b,t,v]),
//        2 = bf16 row-major
// ---------------------------------------------------------------------------
__global__ __launch_bounds__(256) void gemm128(
    const u16* __restrict__ A, const u16* __restrict__ Bw,
    const float* __restrict__ bias, void* __restrict__ Cv,
    int N, int K, int cmode)
{
    __shared__ u16 As[128 * 40];
    __shared__ u16 Bs[128 * 40];
    const int tid = threadIdx.x;
    const int n0 = blockIdx.x * 128, m0 = blockIdx.y * 128;
    const int wave = tid >> 6, lane = tid & 63;
    const int wm = wave & 1, wn = wave >> 1;
    const int l16 = lane & 15, qd = lane >> 4;
    f32x4 acc[4][4] = {};

    const int arow = tid >> 1;            // 0..127
    const int akc = (tid & 1) * 16;       // elem offset 0 or 16 within 32-elem row
    const u16* gA = A + (size_t)(m0 + arow) * K + akc;
    const u16* gB = Bw + (size_t)(n0 + arow) * K + akc;

    for (int k0 = 0; k0 < K; k0 += 32) {
        uint4 av0 = *(const uint4*)(gA + k0);
        uint4 av1 = *(const uint4*)(gA + k0 + 8);
        uint4 bv0 = *(const uint4*)(gB + k0);
        uint4 bv1 = *(const uint4*)(gB + k0 + 8);
        __syncthreads();
        *(uint4*)&As[arow * 40 + akc]     = av0;
        *(uint4*)&As[arow * 40 + akc + 8] = av1;
        *(uint4*)&Bs[arow * 40 + akc]     = bv0;
        *(uint4*)&Bs[arow * 40 + akc + 8] = bv1;
        __syncthreads();
        short8 af[4], bfr[4];
#pragma unroll
        for (int i = 0; i < 4; i++)
            af[i] = *(const short8*)&As[(wm * 64 + i * 16 + l16) * 40 + qd * 8];
#pragma unroll
        for (int i = 0; i < 4; i++)
            bfr[i] = *(const short8*)&Bs[(wn * 64 + i * 16 + l16) * 40 + qd * 8];
#pragma unroll
        for (int mi = 0; mi < 4; mi++)
#pragma unroll
            for (int ni = 0; ni < 4; ni++)
                acc[mi][ni] = __builtin_amdgcn_mfma_f32_16x16x32_bf16(
                    af[mi], bfr[ni], acc[mi][ni], 0, 0, 0);
    }

#pragma unroll
    for (int mi = 0; mi < 4; mi++) {
#pragma unroll
        for (int ni = 0; ni < 4; ni++) {
            int ncol = n0 + wn * 64 + ni * 16 + l16;
            float bv = bias ? bias[ncol] : 0.f;
#pragma unroll
            for (int r = 0; r < 4; r++) {
                int mrow = m0 + wm * 64 + mi * 16 + qd * 4 + r;
                float v = acc[mi][ni][r] + bv;
                if (cmode == 0) {
                    ((float*)Cv)[(size_t)mrow * N + ncol] = v;
                } else if (cmode == 1) {
                    int tt = mrow >> 5, bb = mrow & 31;
                    ((float*)Cv)[((size_t)bb * T_ + tt) * V_ + ncol] = v;
                } else {
                    ((u16*)Cv)[(size_t)mrow * N + ncol] = f2bf(v);
                }
            }
        }
    }
}

// ---------------------------------------------------------------------------
// grid barrier, contention-free:
//   arrival  flags bar[blk*16]        (blk 1..255), polled by block0 threads
//   release  flags bar[(256+blk)*16]  (blk 1..255), one line per spinner
// RELAXED polls; one fence(release)/fence(acquire) per block per barrier.
// ---------------------------------------------------------------------------
__device__ inline void gbar(int* bar, int sense)
{
    __syncthreads();
    const int tid = threadIdx.x;
    if (blockIdx.x == 0) {
        if (tid == 0) __builtin_amdgcn_fence(__ATOMIC_RELEASE, "agent");
        if (tid > 0) {
            while (__hip_atomic_load(&bar[tid * 16], __ATOMIC_RELAXED,
                                     __HIP_MEMORY_SCOPE_AGENT) < sense)
                __builtin_amdgcn_s_sleep(2);
        }
        __syncthreads();
        if (tid > 0)
            __hip_atomic_store(&bar[(256 + tid) * 16], sense, __ATOMIC_RELAXED,
                               __HIP_MEMORY_SCOPE_AGENT);
        if (tid == 0) __builtin_amdgcn_fence(__ATOMIC_ACQUIRE, "agent");
        __syncthreads();
    } else {
        if (tid == 0) {
            __builtin_amdgcn_fence(__ATOMIC_RELEASE, "agent");
            __hip_atomic_store(&bar[blockIdx.x * 16], sense, __ATOMIC_RELAXED,
                               __HIP_MEMORY_SCOPE_AGENT);
            asm volatile("" ::: "memory");
            while (__hip_atomic_load(&bar[(256 + blockIdx.x) * 16], __ATOMIC_RELAXED,
                                     __HIP_MEMORY_SCOPE_AGENT) < sense)
                __builtin_amdgcn_s_sleep(2);
            __builtin_amdgcn_fence(__ATOMIC_ACQUIRE, "agent");
        }
        __syncthreads();
    }
}

// ---------------------------------------------------------------------------
// Persistent decode loop: 256 blocks x 256 threads, all 64 steps.
// Block blk: phase A owns qg cols [blk*16, blk*16+16) (Wcat slice in VGPRs).
//            phases B/C: b = blk>>3, g = blk&7 (s-slice / j-slice per g).
// E2 slice (48KB) and Uk slice (32KB) staged once in LDS.
// Per step: A -> grid bar -> B -> 8-block mini bar (sc only) -> C -> grid bar.
// ---------------------------------------------------------------------------
__global__ __launch_bounds__(256) void k_loop(
    const u16* __restrict__ Wcat, const float* __restrict__ bcat,
    const float* __restrict__ Uk, const float* __restrict__ Va_w,
    const float* __restrict__ Va_b, const u16* __restrict__ E2,
    const float* __restrict__ gix, float* __restrict__ qg,
    float* __restrict__ sc, float* __restrict__ hstate,
    u16* __restrict__ hB, u16* __restrict__ Hall,
    float* __restrict__ out_attn, float* __restrict__ out_hT,
    int* __restrict__ bar)
{
    __shared__ __align__(16) u16 e2s[64 * 384];     // 48KB: [s][seg][jj]
    __shared__ __align__(16) float uks[8 * 1024];   // 32KB: Uk rows g*8..g*8+8 of batch b
    __shared__ float red[4][32][16];                // 8KB phase-A cross-wave partials
    __shared__ float wl[64];
    __shared__ float pu[3][128];

    const int tid = threadIdx.x;
    const int blk = blockIdx.x;
    const int wave = tid >> 6, lane = tid & 63;
    const int l16 = lane & 15, qd = lane >> 4;
    const int b = blk >> 3, g = blk & 7;
    int* mb = bar + 8192;                           // mini-barrier flags

    // --- startup: Wcat B-fragments in registers (reused all 64 steps) ---
    short8 breg[8];
    {
        const u16* wc = Wcat + (size_t)(blk * 16 + l16) * H_ + wave * 256 + qd * 8;
#pragma unroll
        for (int ks = 0; ks < 8; ks++) breg[ks] = *(const short8*)(wc + ks * 32);
    }
    float va[16];
#pragma unroll
    for (int i = 0; i < 16; i++) va[i] = Va_w[i * 64 + lane];
    const float vab = Va_b[0];
    const float bc0 = bcat[blk * 16 + (tid & 15)];   // n = tid&15 for both outputs

    // --- stage E2 slice (once) ---
    {
        const u16* e2g = E2 + (size_t)b * S_ * 3072 + g * 128;
#pragma unroll
        for (int c = 0; c < 12; c++) {
            int o = (c * 256 + tid) * 8;          // u16 offset within slice
            int s = o / 384, rem = o - s * 384;   // 384 u16 per s (3 x 128)
            *(uint4*)&e2s[o] =
                *(const uint4*)(e2g + (size_t)s * 3072 + (rem >> 7) * 1024 + (rem & 127));
        }
    }
    // --- stage Uk slice (once): rows (b, g*8..g*8+8), constant across steps ---
    {
        const float* ukg = Uk + ((size_t)b * S_ + g * 8) * H_;
#pragma unroll
        for (int c = 0; c < 8; c++) {
            int idx = c * 256 + tid;              // float4 units, 2048 total
            ((float4*)uks)[idx] = ((const float4*)ukg)[idx];
        }
    }

    int sense = 0;
    for (int t = 0; t < T_; t++) {
        // ---- phase A: qg[32, blk*16..+16] = hB @ Wcat_slice^T + bcat ----
        f32x4 acc0 = {}, acc1 = {};
        {
            const u16* ha = hB + (size_t)l16 * H_ + wave * 256 + qd * 8;
#pragma unroll
            for (int ks = 0; ks < 8; ks++) {
                short8 a0 = *(const short8*)(ha + ks * 32);
                short8 a1 = *(const short8*)(ha + 16 * H_ + ks * 32);
                acc0 = __builtin_amdgcn_mfma_f32_16x16x32_bf16(a0, breg[ks], acc0, 0, 0, 0);
                acc1 = __builtin_amdgcn_mfma_f32_16x16x32_bf16(a1, breg[ks], acc1, 0, 0, 0);
            }
        }
#pragma unroll
        for (int r = 0; r < 4; r++) {
            red[wave][qd * 4 + r][l16] = acc0[r];
            red[wave][16 + qd * 4 + r][l16] = acc1[r];
        }
        __syncthreads();
        {
            int m = tid >> 4, n = tid & 15;
            float v0 = red[0][m][n] + red[1][m][n] + red[2][m][n] + red[3][m][n] + bc0;
            float v1 = red[0][m + 16][n] + red[1][m + 16][n] +
                       red[2][m + 16][n] + red[3][m + 16][n] + bc0;
            qg[(size_t)m * 4096 + blk * 16 + n] = v0;
            qg[(size_t)(m + 16) * 4096 + blk * 16 + n] = v1;
        }
        gbar(bar, ++sense);

        // ---- phase B: scores for (b, s in [g*8, g*8+8)), Uk from LDS ----
        {
            float qreg[16];
            const float* qb = qg + (size_t)b * 4096;
#pragma unroll
            for (int i = 0; i < 16; i++) qreg[i] = qb[i * 64 + lane];
#pragma unroll
            for (int j2 = 0; j2 < 2; j2++) {
                int sl = wave * 2 + j2;
                const float* uk = uks + sl * 1024;
                float p = 0.f;
#pragma unroll 4
                for (int i = 0; i < 16; i++)
                    p += va[i] * ftanh(qreg[i] + uk[i * 64 + lane]);
#pragma unroll
                for (int m = 1; m < 64; m <<= 1) p += __shfl_xor(p, m);
                if (lane == 0) sc[b * S_ + g * 8 + sl] = p + vab;
            }
        }
        // ---- mini-barrier among the 8 sibling blocks (b, 0..7): sc only ----
        __syncthreads();
        if (tid == 0) {
            __builtin_amdgcn_fence(__ATOMIC_RELEASE, "agent");
            __hip_atomic_store(&mb[(b * 8 + g) * 16], t + 1, __ATOMIC_RELAXED,
                               __HIP_MEMORY_SCOPE_AGENT);
        }
        asm volatile("" ::: "memory");
        if (tid < 8) {
            while (__hip_atomic_load(&mb[(b * 8 + tid) * 16], __ATOMIC_RELAXED,
                                     __HIP_MEMORY_SCOPE_AGENT) <= t)
                __builtin_amdgcn_s_sleep(2);
        }
        if (tid == 0) __builtin_amdgcn_fence(__ATOMIC_ACQUIRE, "agent");
        __syncthreads();

        // ---- phase C: softmax + ctx@W_ih (via E2) + GRU gates + h update ----
        if (tid < 64) {
            float x = sc[b * S_ + tid];
            float mx = x;
#pragma unroll
            for (int m = 1; m < 64; m <<= 1) mx = fmaxf(mx, __shfl_xor(mx, m));
            float e = __expf(x - mx);
            float ssum = e;
#pragma unroll
            for (int m = 1; m < 64; m <<= 1) ssum += __shfl_xor(ssum, m);
            float w = e / ssum;
            wl[tid] = w;
            if (g == 0) out_attn[(size_t)b * T_ * S_ + (size_t)t * S_ + tid] = w;
        }
        __syncthreads();
        {
            int jj = tid & 127, sh = tid >> 7;
            float p0 = 0.f, p1 = 0.f, p2 = 0.f;
            const u16* e0 = &e2s[sh * 32 * 384 + jj];
#pragma unroll 8
            for (int s = 0; s < 32; s++) {
                float w = wl[sh * 32 + s];
                p0 += w * bf2f(e0[s * 384]);
                p1 += w * bf2f(e0[s * 384 + 128]);
                p2 += w * bf2f(e0[s * 384 + 256]);
            }
            if (sh) { pu[0][jj] = p0; pu[1][jj] = p1; pu[2][jj] = p2; }
            __syncthreads();
            if (!sh) {
                int j = g * 128 + jj;
                const float* gi = gix + ((size_t)t * B_ + b) * 3072;
                const float* gh = qg + (size_t)b * 4096 + 1024;
                float r = fsigm(p0 + pu[0][jj] + gi[j] + gh[j]);
                float z = fsigm(p1 + pu[1][jj] + gi[1024 + j] + gh[1024 + j]);
                float n = ftanh(p2 + pu[2][jj] + gi[2048 + j] + r * gh[2048 + j]);
                float hp = hstate[b * H_ + j];
                float hn = (1.f - z) * n + z * hp;
                hstate[b * H_ + j] = hn;
                hB[b * H_ + j] = f2bf(hn);
                Hall[((size_t)t * B_ + b) * H_ + j] = f2bf(hn);
                if (t == T_ - 1) out_hT[b * H_ + j] = hn;
            }
        }
        gbar(bar, ++sense);
    }
}

// ---------------------------------------------------------------------------
// prologue helpers
// ---------------------------------------------------------------------------
__global__ __launch_bounds__(256) void k_gather(
    const float* __restrict__ emb, const int* __restrict__ target,
    u16* __restrict__ XB)
{
    int m = blockIdx.x;           // 0..2047, m = t*32+b
    int t = m >> 5, b = m & 31;
    int tok = (t == 0) ? 1 : target[b * T_ + (t - 1)];
    float4 v = ((const float4*)(emb + (size_t)tok * H_))[threadIdx.x];
    ushort4 o = { f2bf(v.x), f2bf(v.y), f2bf(v.z), f2bf(v.w) };
    *(ushort4*)&XB[(size_t)m * H_ + threadIdx.x * 4] = o;
}

__global__ __launch_bounds__(256) void k_f2b(
    const float* __restrict__ src, u16* __restrict__ dst, int n4)
{
    int i = blockIdx.x * 256 + threadIdx.x;
    int stride = gridDim.x * 256;
    for (; i < n4; i += stride) {
        float4 v = ((const float4*)src)[i];
        ushort4 o = { f2bf(v.x), f2bf(v.y), f2bf(v.z), f2bf(v.w) };
        ((ushort4*)dst)[i] = o;
    }
}

__global__ __launch_bounds__(256) void k_split(
    const float* __restrict__ W, u16* __restrict__ Wx, u16* __restrict__ Wc)
{
    const int n4 = 3072 * 512;    // W_ih is [3072, 2048] -> 512 float4 per row
    int i = blockIdx.x * 256 + threadIdx.x;
    int stride = gridDim.x * 256;
    for (; i < n4; i += stride) {
        int row = i >> 9;
        int c4 = i & 511;
        float4 v = ((const float4*)W)[i];
        ushort4 o = { f2bf(v.x), f2bf(v.y), f2bf(v.z), f2bf(v.w) };
        if (c4 < 256) *(ushort4*)&Wx[(size_t)row * H_ + c4 * 4] = o;
        else          *(ushort4*)&Wc[(size_t)row * H_ + (c4 - 256) * 4] = o;
    }
}

__global__ __launch_bounds__(256) void k_misc(
    const float* __restrict__ Wa_b, const float* __restrict__ b_hh,
    const float* __restrict__ ehid, float* __restrict__ bcat,
    float* __restrict__ hstate, u16* __restrict__ hB, int* __restrict__ bar)
{
    int i = blockIdx.x * 256 + threadIdx.x;   // grid 128 -> 32768 threads
    if (i < 4096) bcat[i] = (i < 1024) ? Wa_b[i] : b_hh[i - 1024];
    if (i < 12352) bar[i] = 0;                // zero all barrier flags each launch
    if (i < 32768) {
        float v = ehid[i];
        hstate[i] = v;
        hB[i] = f2bf(v);
    }
}

// ---------------------------------------------------------------------------
extern "C" void kernel_launch(void* const* d_in, const int* in_sizes, int n_in,
                              void* d_out, int out_size, void* d_ws, size_t ws_size,
                              hipStream_t stream)
{
    const float* enc   = (const float*)d_in[0];
    const float* ehid  = (const float*)d_in[1];
    const int*   tgt   = (const int*)d_in[2];
    const float* emb   = (const float*)d_in[3];
    const float* Wa_w  = (const float*)d_in[4];
    const float* Wa_b  = (const float*)d_in[5];
    const float* Ua_w  = (const float*)d_in[6];
    const float* Ua_b  = (const float*)d_in[7];
    const float* Va_w  = (const float*)d_in[8];
    const float* Va_b  = (const float*)d_in[9];
    const float* W_ih  = (const float*)d_in[10];
    const float* W_hh  = (const float*)d_in[11];
    const float* b_ih  = (const float*)d_in[12];
    const float* b_hh  = (const float*)d_in[13];
    const float* out_w = (const float*)d_in[14];
    const float* out_b = (const float*)d_in[15];

    char* ws = (char*)d_ws;
    size_t off = 0;
    auto alloc = [&](size_t bytes) {
        void* p = ws + off;
        off += (bytes + 255) & ~(size_t)255;
        return p;
    };
    u16* outB  = (u16*)alloc((size_t)V_ * H_ * 2);
    u16* encB  = (u16*)alloc((size_t)B_ * S_ * H_ * 2);
    u16* UaB   = (u16*)alloc((size_t)H_ * H_ * 2);
    u16* WxB   = (u16*)alloc((size_t)3 * H_ * H_ * 2);
    u16* WcB   = (u16*)alloc((size_t)3 * H_ * H_ * 2);
    u16* WcatB = (u16*)alloc((size_t)4 * H_ * H_ * 2);
    u16* XB    = (u16*)alloc((size_t)T_ * B_ * H_ * 2);
    u16* Hall  = (u16*)alloc((size_t)T_ * B_ * H_ * 2);
    u16* hB    = (u16*)alloc((size_t)B_ * H_ * 2);
    u16* E2    = (u16*)alloc((size_t)B_ * S_ * 3 * H_ * 2);
    float* Uk     = (float*)alloc((size_t)B_ * S_ * H_ * 4);
    float* gix    = (float*)alloc((size_t)T_ * B_ * 3 * H_ * 4);
    float* qg     = (float*)alloc((size_t)B_ * 4 * H_ * 4);
    float* hstate = (float*)alloc((size_t)B_ * H_ * 4);
    float* bcat   = (float*)alloc((size_t)4 * H_ * 4);
    float* sc     = (float*)alloc((size_t)B_ * S_ * 4);
    int*   bar    = (int*)alloc((size_t)12352 * 4 + 256);

    float* out_logits = (float*)d_out;
    float* out_hT     = out_logits + (size_t)B_ * T_ * V_;
    float* out_attn   = out_hT + (size_t)B_ * H_;

    // --- prologue: conversions / gathers ---
    k_f2b<<<512, 256, 0, stream>>>(out_w, outB, V_ * H_ / 4);
    k_f2b<<<256, 256, 0, stream>>>(enc, encB, B_ * S_ * H_ / 4);
    k_f2b<<<128, 256, 0, stream>>>(Ua_w, UaB, H_ * H_ / 4);
    k_split<<<512, 256, 0, stream>>>(W_ih, WxB, WcB);
    k_f2b<<<128, 256, 0, stream>>>(Wa_w, WcatB, H_ * H_ / 4);
    k_f2b<<<256, 256, 0, stream>>>(W_hh, WcatB + (size_t)H_ * H_, 3 * H_ * H_ / 4);
    k_gather<<<2048, 256, 0, stream>>>(emb, tgt, XB);
    k_misc<<<128, 256, 0, stream>>>(Wa_b, b_hh, ehid, bcat, hstate, hB, bar);

    // --- prologue GEMMs (M = 2048 in all cases) ---
    gemm128<<<dim3(H_ / 128, 16), 256, 0, stream>>>(encB, UaB, Ua_b, (void*)Uk, H_, H_, 0);
    gemm128<<<dim3(3 * H_ / 128, 16), 256, 0, stream>>>(encB, WcB, (const float*)nullptr, (void*)E2, 3 * H_, H_, 2);
    gemm128<<<dim3(3 * H_ / 128, 16), 256, 0, stream>>>(XB, WxB, b_ih, (void*)gix, 3 * H_, H_, 0);

    // --- persistent decode loop: one cooperative kernel for all 64 steps ---
    {
        void* args[] = {
            (void*)&WcatB, (void*)&bcat, (void*)&Uk, (void*)&Va_w, (void*)&Va_b,
            (void*)&E2, (void*)&gix, (void*)&qg, (void*)&sc, (void*)&hstate,
            (void*)&hB, (void*)&Hall, (void*)&out_attn, (void*)&out_hT, (void*)&bar
        };
        hipLaunchCooperativeKernel((const void*)k_loop, dim3(256), dim3(256),
                                   args, 0, stream);
    }

    // --- batched logits GEMM: [2048,1024] @ [32000,1024]^T -> scatter [B,T,V] ---
    gemm128<<<dim3(V_ / 128, 16), 256, 0, stream>>>(Hall, outB, out_b, (void*)out_logits, V_, H_, 1);
}

// Round 3
// 1762.038 us; speedup vs baseline: 1.9339x; 1.4674x over previous
//
#include <hip/hip_runtime.h>

#define B_ 32
#define S_ 64
#define T_ 64
#define H_ 1024
#define V_ 32000

typedef unsigned short u16;
typedef unsigned long long u64t;
typedef short short8 __attribute__((ext_vector_type(8)));
typedef float f32x4 __attribute__((ext_vector_type(4)));

__device__ inline float bf2f(u16 u) {
    union { unsigned int ui; float f; } c; c.ui = ((unsigned int)u) << 16; return c.f;
}
__device__ inline u16 f2bf(float f) {
    union { float f; unsigned int u; } c; c.f = f;
    unsigned int u = c.u;
    u += 0x7FFFu + ((u >> 16) & 1u);
    return (u16)(u >> 16);
}
__device__ inline float ftanh(float x) {
    float ax = fabsf(x);
    float e = __expf(-2.f * ax);
    float r = (1.f - e) / (1.f + e);
    return copysignf(r, x);
}
__device__ inline float fsigm(float x) { return 1.f / (1.f + __expf(-x)); }

// coherent (agent-scope, fence-free) helpers: relaxed atomics emit sc1 accesses
__device__ inline float cld_f(const float* p) {
    return __hip_atomic_load(p, __ATOMIC_RELAXED, __HIP_MEMORY_SCOPE_AGENT);
}
__device__ inline void cst_f(float* p, float v) {
    __hip_atomic_store(p, v, __ATOMIC_RELAXED, __HIP_MEMORY_SCOPE_AGENT);
}
__device__ inline void cst_u(unsigned* p, unsigned v) {
    __hip_atomic_store(p, v, __ATOMIC_RELAXED, __HIP_MEMORY_SCOPE_AGENT);
}
__device__ inline short8 cld_s8(const u16* p) {
    union { u64t q[2]; short8 v; } u;
    u.q[0] = __hip_atomic_load((const u64t*)p, __ATOMIC_RELAXED, __HIP_MEMORY_SCOPE_AGENT);
    u.q[1] = __hip_atomic_load((const u64t*)(p + 4), __ATOMIC_RELAXED, __HIP_MEMORY_SCOPE_AGENT);
    return u.v;
}

// ---------------------------------------------------------------------------
// Generic 128x128 bf16 MFMA GEMM: C[M=2048,N] = A[2048,K] @ B[N,K]^T + bias
// cmode: 0 = f32 row-major, 1 = logits scatter (m -> t*32+b, write [b,t,v]),
//        2 = bf16 row-major
// ---------------------------------------------------------------------------
__global__ __launch_bounds__(256) void gemm128(
    const u16* __restrict__ A, const u16* __restrict__ Bw,
    const float* __restrict__ bias, void* __restrict__ Cv,
    int N, int K, int cmode)
{
    __shared__ u16 As[128 * 40];
    __shared__ u16 Bs[128 * 40];
    const int tid = threadIdx.x;
    const int n0 = blockIdx.x * 128, m0 = blockIdx.y * 128;
    const int wave = tid >> 6, lane = tid & 63;
    const int wm = wave & 1, wn = wave >> 1;
    const int l16 = lane & 15, qd = lane >> 4;
    f32x4 acc[4][4] = {};

    const int arow = tid >> 1;            // 0..127
    const int akc = (tid & 1) * 16;       // elem offset 0 or 16 within 32-elem row
    const u16* gA = A + (size_t)(m0 + arow) * K + akc;
    const u16* gB = Bw + (size_t)(n0 + arow) * K + akc;

    for (int k0 = 0; k0 < K; k0 += 32) {
        uint4 av0 = *(const uint4*)(gA + k0);
        uint4 av1 = *(const uint4*)(gA + k0 + 8);
        uint4 bv0 = *(const uint4*)(gB + k0);
        uint4 bv1 = *(const uint4*)(gB + k0 + 8);
        __syncthreads();
        *(uint4*)&As[arow * 40 + akc]     = av0;
        *(uint4*)&As[arow * 40 + akc + 8] = av1;
        *(uint4*)&Bs[arow * 40 + akc]     = bv0;
        *(uint4*)&Bs[arow * 40 + akc + 8] = bv1;
        __syncthreads();
        short8 af[4], bfr[4];
#pragma unroll
        for (int i = 0; i < 4; i++)
            af[i] = *(const short8*)&As[(wm * 64 + i * 16 + l16) * 40 + qd * 8];
#pragma unroll
        for (int i = 0; i < 4; i++)
            bfr[i] = *(const short8*)&Bs[(wn * 64 + i * 16 + l16) * 40 + qd * 8];
#pragma unroll
        for (int mi = 0; mi < 4; mi++)
#pragma unroll
            for (int ni = 0; ni < 4; ni++)
                acc[mi][ni] = __builtin_amdgcn_mfma_f32_16x16x32_bf16(
                    af[mi], bfr[ni], acc[mi][ni], 0, 0, 0);
    }

#pragma unroll
    for (int mi = 0; mi < 4; mi++) {
#pragma unroll
        for (int ni = 0; ni < 4; ni++) {
            int ncol = n0 + wn * 64 + ni * 16 + l16;
            float bv = bias ? bias[ncol] : 0.f;
#pragma unroll
            for (int r = 0; r < 4; r++) {
                int mrow = m0 + wm * 64 + mi * 16 + qd * 4 + r;
                float v = acc[mi][ni][r] + bv;
                if (cmode == 0) {
                    ((float*)Cv)[(size_t)mrow * N + ncol] = v;
                } else if (cmode == 1) {
                    int tt = mrow >> 5, bb = mrow & 31;
                    ((float*)Cv)[((size_t)bb * T_ + tt) * V_ + ncol] = v;
                } else {
                    ((u16*)Cv)[(size_t)mrow * N + ncol] = f2bf(v);
                }
            }
        }
    }
}

// ---------------------------------------------------------------------------
// grid barrier, FENCE-FREE: all cross-block data uses sc1 (agent-coherent)
// accesses, so the barrier is a pure flag protocol.
//   arrival  flags bar[blk*16]        (blk 1..255), polled by block0 threads
//   release  flags bar[(256+blk)*16]  (blk 1..255), one line per spinner
// Producer correctness: s_waitcnt vmcnt(0) before syncthreads ensures all
// write-through data stores reached the coherence point before flag store.
// ---------------------------------------------------------------------------
__device__ inline void gbar(int* bar, int sense)
{
    asm volatile("s_waitcnt vmcnt(0)" ::: "memory");
    __syncthreads();
    const int tid = threadIdx.x;
    if (blockIdx.x == 0) {
        if (tid > 0) {
            while (__hip_atomic_load(&bar[tid * 16], __ATOMIC_RELAXED,
                                     __HIP_MEMORY_SCOPE_AGENT) < sense)
                __builtin_amdgcn_s_sleep(1);
        }
        __syncthreads();
        if (tid > 0)
            __hip_atomic_store(&bar[(256 + tid) * 16], sense, __ATOMIC_RELAXED,
                               __HIP_MEMORY_SCOPE_AGENT);
    } else {
        if (tid == 0) {
            __hip_atomic_store(&bar[blockIdx.x * 16], sense, __ATOMIC_RELAXED,
                               __HIP_MEMORY_SCOPE_AGENT);
            while (__hip_atomic_load(&bar[(256 + blockIdx.x) * 16], __ATOMIC_RELAXED,
                                     __HIP_MEMORY_SCOPE_AGENT) < sense)
                __builtin_amdgcn_s_sleep(1);
        }
        __syncthreads();
    }
}

// ---------------------------------------------------------------------------
// Persistent decode loop: 256 blocks x 256 threads, all 64 steps.
// Block blk: phase A owns qg cols [blk*16, blk*16+16) (Wcat slice in VGPRs).
//            phases B/C: b = blk>>3, g = blk&7 (s-slice / j-slice per g).
// E2 slice (48KB) and Uk slice (32KB) staged once in LDS.
// Cross-block traffic (hB, qg, sc) via agent-coherent relaxed atomics.
// ---------------------------------------------------------------------------
__global__ __launch_bounds__(256) void k_loop(
    const u16* __restrict__ Wcat, const float* __restrict__ bcat,
    const float* __restrict__ Uk, const float* __restrict__ Va_w,
    const float* __restrict__ Va_b, const u16* __restrict__ E2,
    const float* __restrict__ gix, float* __restrict__ qg,
    float* __restrict__ sc, float* __restrict__ hstate,
    u16* __restrict__ hB, u16* __restrict__ Hall,
    float* __restrict__ out_attn, float* __restrict__ out_hT,
    int* __restrict__ bar)
{
    __shared__ __align__(16) u16 e2s[64 * 384];     // 48KB: [s][seg][jj]
    __shared__ __align__(16) float uks[8 * 1024];   // 32KB: Uk rows g*8..g*8+8 of batch b
    __shared__ float red[4][32][16];                // 8KB phase-A cross-wave partials
    __shared__ float wl[64];
    __shared__ float pu[3][128];

    const int tid = threadIdx.x;
    const int blk = blockIdx.x;
    const int wave = tid >> 6, lane = tid & 63;
    const int l16 = lane & 15, qd = lane >> 4;
    const int b = blk >> 3, g = blk & 7;
    int* mb = bar + 8192;                           // mini-barrier flags

    // --- startup: Wcat B-fragments in registers (reused all 64 steps) ---
    short8 breg[8];
    {
        const u16* wc = Wcat + (size_t)(blk * 16 + l16) * H_ + wave * 256 + qd * 8;
#pragma unroll
        for (int ks = 0; ks < 8; ks++) breg[ks] = *(const short8*)(wc + ks * 32);
    }
    float va[16];
#pragma unroll
    for (int i = 0; i < 16; i++) va[i] = Va_w[i * 64 + lane];
    const float vab = Va_b[0];
    const float bc0 = bcat[blk * 16 + (tid & 15)];   // n = tid&15 for both outputs

    // --- stage E2 slice (once) ---
    {
        const u16* e2g = E2 + (size_t)b * S_ * 3072 + g * 128;
#pragma unroll
        for (int c = 0; c < 12; c++) {
            int o = (c * 256 + tid) * 8;          // u16 offset within slice
            int s = o / 384, rem = o - s * 384;   // 384 u16 per s (3 x 128)
            *(uint4*)&e2s[o] =
                *(const uint4*)(e2g + (size_t)s * 3072 + (rem >> 7) * 1024 + (rem & 127));
        }
    }
    // --- stage Uk slice (once): rows (b, g*8..g*8+8), constant across steps ---
    {
        const float* ukg = Uk + ((size_t)b * S_ + g * 8) * H_;
#pragma unroll
        for (int c = 0; c < 8; c++) {
            int idx = c * 256 + tid;              // float4 units, 2048 total
            ((float4*)uks)[idx] = ((const float4*)ukg)[idx];
        }
    }

    int sense = 0;
    for (int t = 0; t < T_; t++) {
        // ---- phase A: qg[32, blk*16..+16] = hB @ Wcat_slice^T + bcat ----
        f32x4 acc0 = {}, acc1 = {};
        {
            const u16* ha = hB + (size_t)l16 * H_ + wave * 256 + qd * 8;
#pragma unroll
            for (int ks = 0; ks < 8; ks++) {
                short8 a0 = cld_s8(ha + ks * 32);
                short8 a1 = cld_s8(ha + 16 * H_ + ks * 32);
                acc0 = __builtin_amdgcn_mfma_f32_16x16x32_bf16(a0, breg[ks], acc0, 0, 0, 0);
                acc1 = __builtin_amdgcn_mfma_f32_16x16x32_bf16(a1, breg[ks], acc1, 0, 0, 0);
            }
        }
#pragma unroll
        for (int r = 0; r < 4; r++) {
            red[wave][qd * 4 + r][l16] = acc0[r];
            red[wave][16 + qd * 4 + r][l16] = acc1[r];
        }
        __syncthreads();
        {
            int m = tid >> 4, n = tid & 15;
            float v0 = red[0][m][n] + red[1][m][n] + red[2][m][n] + red[3][m][n] + bc0;
            float v1 = red[0][m + 16][n] + red[1][m + 16][n] +
                       red[2][m + 16][n] + red[3][m + 16][n] + bc0;
            cst_f(&qg[(size_t)m * 4096 + blk * 16 + n], v0);
            cst_f(&qg[(size_t)(m + 16) * 4096 + blk * 16 + n], v1);
        }
        gbar(bar, ++sense);

        // ---- phase B: scores for (b, s in [g*8, g*8+8)), Uk from LDS ----
        {
            float qreg[16];
            const float* qb = qg + (size_t)b * 4096;
#pragma unroll
            for (int i = 0; i < 16; i++) qreg[i] = cld_f(qb + i * 64 + lane);
#pragma unroll
            for (int j2 = 0; j2 < 2; j2++) {
                int sl = wave * 2 + j2;
                const float* uk = uks + sl * 1024;
                float p = 0.f;
#pragma unroll 4
                for (int i = 0; i < 16; i++)
                    p += va[i] * ftanh(qreg[i] + uk[i * 64 + lane]);
#pragma unroll
                for (int m = 1; m < 64; m <<= 1) p += __shfl_xor(p, m);
                if (lane == 0) cst_f(&sc[b * S_ + g * 8 + sl], p + vab);
            }
        }
        // ---- mini-barrier among the 8 sibling blocks (b, 0..7): sc only ----
        asm volatile("s_waitcnt vmcnt(0)" ::: "memory");
        __syncthreads();
        if (tid == 0)
            __hip_atomic_store(&mb[(b * 8 + g) * 16], t + 1, __ATOMIC_RELAXED,
                               __HIP_MEMORY_SCOPE_AGENT);
        if (tid < 8) {
            while (__hip_atomic_load(&mb[(b * 8 + tid) * 16], __ATOMIC_RELAXED,
                                     __HIP_MEMORY_SCOPE_AGENT) <= t)
                __builtin_amdgcn_s_sleep(1);
        }
        __syncthreads();

        // ---- phase C: softmax + ctx@W_ih (via E2) + GRU gates + h update ----
        if (tid < 64) {
            float x = cld_f(&sc[b * S_ + tid]);
            float mx = x;
#pragma unroll
            for (int m = 1; m < 64; m <<= 1) mx = fmaxf(mx, __shfl_xor(mx, m));
            float e = __expf(x - mx);
            float ssum = e;
#pragma unroll
            for (int m = 1; m < 64; m <<= 1) ssum += __shfl_xor(ssum, m);
            float w = e / ssum;
            wl[tid] = w;
            if (g == 0) out_attn[(size_t)b * T_ * S_ + (size_t)t * S_ + tid] = w;
        }
        __syncthreads();
        {
            int jj = tid & 127, sh = tid >> 7;
            float p0 = 0.f, p1 = 0.f, p2 = 0.f;
            const u16* e0 = &e2s[sh * 32 * 384 + jj];
#pragma unroll 8
            for (int s = 0; s < 32; s++) {
                float w = wl[sh * 32 + s];
                p0 += w * bf2f(e0[s * 384]);
                p1 += w * bf2f(e0[s * 384 + 128]);
                p2 += w * bf2f(e0[s * 384 + 256]);
            }
            if (sh) { pu[0][jj] = p0; pu[1][jj] = p1; pu[2][jj] = p2; }
            __syncthreads();
            if (!sh) {
                int j = g * 128 + jj;
                const float* gi = gix + ((size_t)t * B_ + b) * 3072;
                const float* gh = qg + (size_t)b * 4096 + 1024;
                float r = fsigm(p0 + pu[0][jj] + gi[j] + cld_f(gh + j));
                float z = fsigm(p1 + pu[1][jj] + gi[1024 + j] + cld_f(gh + 1024 + j));
                float n = ftanh(p2 + pu[2][jj] + gi[2048 + j] + r * cld_f(gh + 2048 + j));
                float hp = hstate[b * H_ + j];
                float hn = (1.f - z) * n + z * hp;
                hstate[b * H_ + j] = hn;
                unsigned hb16 = f2bf(hn);
                unsigned nb = __shfl_down(hb16, 1);
                if (!(jj & 1))
                    cst_u((unsigned*)&hB[b * H_ + j], hb16 | (nb << 16));
                Hall[((size_t)t * B_ + b) * H_ + j] = f2bf(hn);
                if (t == T_ - 1) out_hT[b * H_ + j] = hn;
            }
        }
        gbar(bar, ++sense);
    }
}

// ---------------------------------------------------------------------------
// prologue helpers
// ---------------------------------------------------------------------------
__global__ __launch_bounds__(256) void k_gather(
    const float* __restrict__ emb, const int* __restrict__ target,
    u16* __restrict__ XB)
{
    int m = blockIdx.x;           // 0..2047, m = t*32+b
    int t = m >> 5, b = m & 31;
    int tok = (t == 0) ? 1 : target[b * T_ + (t - 1)];
    float4 v = ((const float4*)(emb + (size_t)tok * H_))[threadIdx.x];
    ushort4 o = { f2bf(v.x), f2bf(v.y), f2bf(v.z), f2bf(v.w) };
    *(ushort4*)&XB[(size_t)m * H_ + threadIdx.x * 4] = o;
}

__global__ __launch_bounds__(256) void k_f2b(
    const float* __restrict__ src, u16* __restrict__ dst, int n4)
{
    int i = blockIdx.x * 256 + threadIdx.x;
    int stride = gridDim.x * 256;
    for (; i < n4; i += stride) {
        float4 v = ((const float4*)src)[i];
        ushort4 o = { f2bf(v.x), f2bf(v.y), f2bf(v.z), f2bf(v.w) };
        ((ushort4*)dst)[i] = o;
    }
}

__global__ __launch_bounds__(256) void k_split(
    const float* __restrict__ W, u16* __restrict__ Wx, u16* __restrict__ Wc)
{
    const int n4 = 3072 * 512;    // W_ih is [3072, 2048] -> 512 float4 per row
    int i = blockIdx.x * 256 + threadIdx.x;
    int stride = gridDim.x * 256;
    for (; i < n4; i += stride) {
        int row = i >> 9;
        int c4 = i & 511;
        float4 v = ((const float4*)W)[i];
        ushort4 o = { f2bf(v.x), f2bf(v.y), f2bf(v.z), f2bf(v.w) };
        if (c4 < 256) *(ushort4*)&Wx[(size_t)row * H_ + c4 * 4] = o;
        else          *(ushort4*)&Wc[(size_t)row * H_ + (c4 - 256) * 4] = o;
    }
}

__global__ __launch_bounds__(256) void k_misc(
    const float* __restrict__ Wa_b, const float* __restrict__ b_hh,
    const float* __restrict__ ehid, float* __restrict__ bcat,
    float* __restrict__ hstate, u16* __restrict__ hB, int* __restrict__ bar)
{
    int i = blockIdx.x * 256 + threadIdx.x;   // grid 128 -> 32768 threads
    if (i < 4096) bcat[i] = (i < 1024) ? Wa_b[i] : b_hh[i - 1024];
    if (i < 12352) bar[i] = 0;                // zero all barrier flags each launch
    if (i < 32768) {
        float v = ehid[i];
        hstate[i] = v;
        hB[i] = f2bf(v);
    }
}

// ---------------------------------------------------------------------------
extern "C" void kernel_launch(void* const* d_in, const int* in_sizes, int n_in,
                              void* d_out, int out_size, void* d_ws, size_t ws_size,
                              hipStream_t stream)
{
    const float* enc   = (const float*)d_in[0];
    const float* ehid  = (const float*)d_in[1];
    const int*   tgt   = (const int*)d_in[2];
    const float* emb   = (const float*)d_in[3];
    const float* Wa_w  = (const float*)d_in[4];
    const float* Wa_b  = (const float*)d_in[5];
    const float* Ua_w  = (const float*)d_in[6];
    const float* Ua_b  = (const float*)d_in[7];
    const float* Va_w  = (const float*)d_in[8];
    const float* Va_b  = (const float*)d_in[9];
    const float* W_ih  = (const float*)d_in[10];
    const float* W_hh  = (const float*)d_in[11];
    const float* b_ih  = (const float*)d_in[12];
    const float* b_hh  = (const float*)d_in[13];
    const float* out_w = (const float*)d_in[14];
    const float* out_b = (const float*)d_in[15];

    char* ws = (char*)d_ws;
    size_t off = 0;
    auto alloc = [&](size_t bytes) {
        void* p = ws + off;
        off += (bytes + 255) & ~(size_t)255;
        return p;
    };
    u16* outB  = (u16*)alloc((size_t)V_ * H_ * 2);
    u16* encB  = (u16*)alloc((size_t)B_ * S_ * H_ * 2);
    u16* UaB   = (u16*)alloc((size_t)H_ * H_ * 2);
    u16* WxB   = (u16*)alloc((size_t)3 * H_ * H_ * 2);
    u16* WcB   = (u16*)alloc((size_t)3 * H_ * H_ * 2);
    u16* WcatB = (u16*)alloc((size_t)4 * H_ * H_ * 2);
    u16* XB    = (u16*)alloc((size_t)T_ * B_ * H_ * 2);
    u16* Hall  = (u16*)alloc((size_t)T_ * B_ * H_ * 2);
    u16* hB    = (u16*)alloc((size_t)B_ * H_ * 2);
    u16* E2    = (u16*)alloc((size_t)B_ * S_ * 3 * H_ * 2);
    float* Uk     = (float*)alloc((size_t)B_ * S_ * H_ * 4);
    float* gix    = (float*)alloc((size_t)T_ * B_ * 3 * H_ * 4);
    float* qg     = (float*)alloc((size_t)B_ * 4 * H_ * 4);
    float* hstate = (float*)alloc((size_t)B_ * H_ * 4);
    float* bcat   = (float*)alloc((size_t)4 * H_ * 4);
    float* sc     = (float*)alloc((size_t)B_ * S_ * 4);
    int*   bar    = (int*)alloc((size_t)12352 * 4 + 256);

    float* out_logits = (float*)d_out;
    float* out_hT     = out_logits + (size_t)B_ * T_ * V_;
    float* out_attn   = out_hT + (size_t)B_ * H_;

    // --- prologue: conversions / gathers ---
    k_f2b<<<512, 256, 0, stream>>>(out_w, outB, V_ * H_ / 4);
    k_f2b<<<256, 256, 0, stream>>>(enc, encB, B_ * S_ * H_ / 4);
    k_f2b<<<128, 256, 0, stream>>>(Ua_w, UaB, H_ * H_ / 4);
    k_split<<<512, 256, 0, stream>>>(W_ih, WxB, WcB);
    k_f2b<<<128, 256, 0, stream>>>(Wa_w, WcatB, H_ * H_ / 4);
    k_f2b<<<256, 256, 0, stream>>>(W_hh, WcatB + (size_t)H_ * H_, 3 * H_ * H_ / 4);
    k_gather<<<2048, 256, 0, stream>>>(emb, tgt, XB);
    k_misc<<<128, 256, 0, stream>>>(Wa_b, b_hh, ehid, bcat, hstate, hB, bar);

    // --- prologue GEMMs (M = 2048 in all cases) ---
    gemm128<<<dim3(H_ / 128, 16), 256, 0, stream>>>(encB, UaB, Ua_b, (void*)Uk, H_, H_, 0);
    gemm128<<<dim3(3 * H_ / 128, 16), 256, 0, stream>>>(encB, WcB, (const float*)nullptr, (void*)E2, 3 * H_, H_, 2);
    gemm128<<<dim3(3 * H_ / 128, 16), 256, 0, stream>>>(XB, WxB, b_ih, (void*)gix, 3 * H_, H_, 0);

    // --- persistent decode loop: one cooperative kernel for all 64 steps ---
    {
        void* args[] = {
            (void*)&WcatB, (void*)&bcat, (void*)&Uk, (void*)&Va_w, (void*)&Va_b,
            (void*)&E2, (void*)&gix, (void*)&qg, (void*)&sc, (void*)&hstate,
            (void*)&hB, (void*)&Hall, (void*)&out_attn, (void*)&out_hT, (void*)&bar
        };
        hipLaunchCooperativeKernel((const void*)k_loop, dim3(256), dim3(256),
                                   args, 0, stream);
    }

    // --- batched logits GEMM: [2048,1024] @ [32000,1024]^T -> scatter [B,T,V] ---
    gemm128<<<dim3(V_ / 128, 16), 256, 0, stream>>>(Hall, outB, out_b, (void*)out_logits, V_, H_, 1);
}